// Round 7
// baseline (474.959 us; speedup 1.0000x reference)
//
#include <hip/hip_runtime.h>
#include <hip/hip_bf16.h>

#define H 16
#define DK 64
#define DM 1024
#define LQ 512
#define LK 2048
#define BSZ 4

typedef __hip_bfloat16 bf16;
typedef __attribute__((ext_vector_type(8))) short short8;
typedef __attribute__((ext_vector_type(4))) short short4v;
typedef __attribute__((ext_vector_type(4))) float f32x4;

// ---------------- fused converts: q,k,v,Wq,Wk,Wv,Wo -> bf16; pack bias/mask; btabT ----------------

__global__ __launch_bounds__(256) void fused_cvt(
    const float* __restrict__ q, const float* __restrict__ k, const float* __restrict__ v,
    const int* __restrict__ bidx, const int* __restrict__ msk,
    const float* __restrict__ Wq, const float* __restrict__ Wk,
    const float* __restrict__ Wv, const float* __restrict__ Wo,
    const float* __restrict__ btab,
    bf16* __restrict__ qb, bf16* __restrict__ kb, bf16* __restrict__ vb,
    bf16* __restrict__ Wqb, bf16* __restrict__ Wkb, bf16* __restrict__ Wvb,
    bf16* __restrict__ Wob, short* __restrict__ pkd, float* __restrict__ btabT) {
  const int blk = blockIdx.x, tid = threadIdx.x;
  const float* src;
  bf16* dst;
  int base;
  if (blk < 2048)       { src = q;  dst = qb;  base = blk; }
  else if (blk < 10240) { src = k;  dst = kb;  base = blk - 2048; }
  else if (blk < 18432) { src = v;  dst = vb;  base = blk - 10240; }
  else if (blk < 19456) { src = Wq; dst = Wqb; base = blk - 18432; }
  else if (blk < 20480) { src = Wk; dst = Wkb; base = blk - 19456; }
  else if (blk < 21504) { src = Wv; dst = Wvb; base = blk - 20480; }
  else if (blk < 22528) { src = Wo; dst = Wob; base = blk - 21504; }
  else if (blk < 26624) {
    int i = (blk - 22528) * 1024 + tid * 4;
    int4 a = *reinterpret_cast<const int4*>(bidx + i);
    int4 m = *reinterpret_cast<const int4*>(msk + i);
    short4 r;
    r.x = m.x ? (short)a.x : (short)-1;
    r.y = m.y ? (short)a.y : (short)-1;
    r.z = m.z ? (short)a.z : (short)-1;
    r.w = m.w ? (short)a.w : (short)-1;
    *reinterpret_cast<short4*>(pkd + i) = r;
    return;
  } else {
    // bias table: transpose + fold the fixed softmax shift (-10)
    for (int j = tid; j < 900 * H; j += 256) {
      int hh = j / 900, i = j - hh * 900;
      btabT[hh * 900 + i] = btab[i * H + hh] - 10.0f;
    }
    return;
  }
  int i = base * 1024 + tid * 4;
  float4 val = *reinterpret_cast<const float4*>(src + i);
  bf16 o0 = __float2bfloat16(val.x), o1 = __float2bfloat16(val.y);
  bf16 o2 = __float2bfloat16(val.z), o3 = __float2bfloat16(val.w);
  short4 pk;
  pk.x = *reinterpret_cast<short*>(&o0);
  pk.y = *reinterpret_cast<short*>(&o1);
  pk.z = *reinterpret_cast<short*>(&o2);
  pk.w = *reinterpret_cast<short*>(&o3);
  *reinterpret_cast<short4*>(reinterpret_cast<short*>(dst) + i) = pk;
}

// ---------------- GEMM: C[m][n] = sum_k A[m][k]*B[n][k] + bias[n] ----------------
// MODE 0: write bf16 head-interleaved  dst[((b*H+h)*Lrows + l)*64 + d]
// MODE 1: write bf16 d-major V        dst[((b*H+h)*64 + d)*LK + key]
// MODE 2: write f32 row-major          dst[row*N + col]
// TM: 128 (4 waves as 2x2, 64x64 each) or 64 (4 waves as 1x4, 64x32 each)

__device__ __forceinline__ void g2lds16(const bf16* g, bf16* l) {
  __builtin_amdgcn_global_load_lds(
      (__attribute__((address_space(1))) void*)(g),
      (__attribute__((address_space(3))) void*)(l), 16, 0, 0);
}

template <int MODE, int TM>
__global__ __launch_bounds__(256) void gemm_bt(const bf16* __restrict__ A,
                                               const bf16* __restrict__ B,
                                               const float* __restrict__ bias,
                                               void* __restrict__ out,
                                               int M, int N, int K, int Lrows) {
  __shared__ bf16 As[TM * 32];
  __shared__ bf16 Bs[128 * 32];
  constexpr int NT = (TM == 128) ? 4 : 2;
  const int tid = threadIdx.x;
  const int wave = tid >> 6, lane = tid & 63;
  const int quad = lane >> 4, l15 = lane & 15;
  const int rowbase = (TM == 128) ? (wave >> 1) * 64 : 0;
  const int colbase = (TM == 128) ? (wave & 1) * 64 : wave * 32;
  const int rowA0 = blockIdx.x * TM, colB0 = blockIdx.y * 128;
  const int srow = lane >> 2, skq = lane & 3;

  f32x4 acc[4][NT];
  const f32x4 zero = {0.f, 0.f, 0.f, 0.f};
  for (int mt = 0; mt < 4; mt++)
    for (int nt = 0; nt < NT; nt++) acc[mt][nt] = zero;

  for (int k0 = 0; k0 < K; k0 += 32) {
    if (TM == 128) {
      for (int c = 0; c < 2; ++c) {
        int r = wave * 32 + c * 16;
        g2lds16(A + (size_t)(rowA0 + r + srow) * K + k0 + skq * 8, As + r * 32);
      }
    } else {
      int r = wave * 16;
      g2lds16(A + (size_t)(rowA0 + r + srow) * K + k0 + skq * 8, As + r * 32);
    }
    for (int c = 0; c < 2; ++c) {
      int r = wave * 32 + c * 16;
      g2lds16(B + (size_t)(colB0 + r + srow) * K + k0 + skq * 8, Bs + r * 32);
    }
    __syncthreads();
    short8 af[4], bfr[NT];
    for (int mt = 0; mt < 4; mt++)
      af[mt] = *reinterpret_cast<const short8*>(As + (rowbase + mt * 16 + l15) * 32 + quad * 8);
    for (int nt = 0; nt < NT; nt++)
      bfr[nt] = *reinterpret_cast<const short8*>(Bs + (colbase + nt * 16 + l15) * 32 + quad * 8);
    for (int mt = 0; mt < 4; mt++)
      for (int nt = 0; nt < NT; nt++)
        acc[mt][nt] = __builtin_amdgcn_mfma_f32_16x16x32_bf16(af[mt], bfr[nt], acc[mt][nt], 0, 0, 0);
    __syncthreads();
  }

  const int bb = (MODE == 2) ? 0 : (rowA0 / Lrows);
  const int lb = (MODE == 2) ? rowA0 : (rowA0 - bb * Lrows);
  for (int nt = 0; nt < NT; nt++) {
    int col = colB0 + colbase + nt * 16 + l15;
    float bv = bias[col];
    int hh = col >> 6, d = col & 63;
    for (int mt = 0; mt < 4; mt++) {
      int lrow0 = lb + rowbase + mt * 16 + quad * 4;
      f32x4 v = acc[mt][nt];
      if (MODE == 1) {
        short4 pkv;
        bf16 t0 = __float2bfloat16(v[0] + bv);
        bf16 t1 = __float2bfloat16(v[1] + bv);
        bf16 t2 = __float2bfloat16(v[2] + bv);
        bf16 t3 = __float2bfloat16(v[3] + bv);
        pkv.x = *reinterpret_cast<short*>(&t0);
        pkv.y = *reinterpret_cast<short*>(&t1);
        pkv.z = *reinterpret_cast<short*>(&t2);
        pkv.w = *reinterpret_cast<short*>(&t3);
        *reinterpret_cast<short4*>((bf16*)out +
            ((size_t)((bb * H + hh) * DK + d)) * LK + lrow0) = pkv;
      } else {
        for (int r = 0; r < 4; r++) {
          float val = v[r] + bv;
          if (MODE == 0) {
            ((bf16*)out)[(((size_t)(bb * H + hh) * Lrows + lrow0 + r) << 6) + d] = __float2bfloat16(val);
          } else {
            ((float*)out)[(size_t)(lrow0 + r) * N + col] = val;
          }
        }
      }
    }
  }
}

// ---------------- attention v4b: S^T formulation, zero-LDS P path ----------------
// Same dataflow as the R5-passing attn4. Two codegen-only changes:
//  * __launch_bounds__(256, 2): VGPR budget 256/wave so all fragments stay live
//  * sched_barrier(0) after the load block: pins V/pk/K-prefetch loads above
//    the exp+PV consumers (R5 showed the scheduler sinking them to their uses,
//    serializing ~16 L2-latency stalls per chunk -> 208us)
// p = exp(s/8 + bias - 10), masked -> 0; partials sum linearly across z.
// Numerics: |score| <~ 6.5 (Cauchy-Schwarz) so exp(s-10) in [e-17, e-3]: safe.

__global__ __launch_bounds__(256, 2) void attn4(const bf16* __restrict__ Qh,
                                                const bf16* __restrict__ Kh,
                                                const bf16* __restrict__ Vt,
                                                const short* __restrict__ pkm,
                                                const float* __restrict__ btabT,
                                                float* __restrict__ Opart,
                                                float* __restrict__ L) {
  __shared__ float bts[900];
  const int tid = threadIdx.x;
  const int wave = tid >> 6, lane = tid & 63;
  const int quad = lane >> 4, l15 = lane & 15;
  const int bh = blockIdx.x, b = bh >> 4, h = bh & 15;
  const int qt = blockIdx.y, z = blockIdx.z;
  const int key_base = z * 512;

  for (int i = tid; i < 900; i += 256) bts[i] = btabT[h * 900 + i];

  const int q = qt * 64 + wave * 16 + l15;  // this lane's q row (j-index)
  // Q as B-operand frags for 16x16x32: B[j=q=l15][k=quad*8+jj]
  short8 qf[2];
  for (int ks = 0; ks < 2; ks++)
    qf[ks] = *reinterpret_cast<const short8*>(
        Qh + ((size_t)bh * LQ + q) * DK + ks * 32 + quad * 8);

  const bf16* kbase = Kh + ((size_t)bh * LK + key_base) * DK;
  const bf16* vbase = Vt + ((size_t)bh * DK) * LK + key_base;
  const short* pkrow = pkm + ((size_t)b * LQ + q) * LK + key_base;

  f32x4 of[4];
  float denom = 0.f;
  const f32x4 zero = {0.f, 0.f, 0.f, 0.f};
  for (int dt = 0; dt < 4; dt++) of[dt] = zero;

  __syncthreads();

  // K as A-operand frags for chunk 0: A[i=key=nt*16+l15][k=quad*8+jj]
  short8 kf[4][2];
  for (int nt = 0; nt < 4; nt++)
    for (int ks = 0; ks < 2; ks++)
      kf[nt][ks] = *reinterpret_cast<const short8*>(
          kbase + (size_t)(nt * 16 + l15) * DK + ks * 32 + quad * 8);

  for (int kc = 0; kc < 8; ++kc) {
    const int key0 = kc * 64;

    // S^T: D[key][q]
    f32x4 sa[4];
    for (int nt = 0; nt < 4; nt++) sa[nt] = zero;
    for (int nt = 0; nt < 4; nt++)
      for (int ks = 0; ks < 2; ks++)
        sa[nt] = __builtin_amdgcn_mfma_f32_16x16x32_bf16(kf[nt][ks], qf[ks], sa[nt], 0, 0, 0);

    // pk indices: 4 consecutive shorts per block -> short4 loads
    short4v pkv[4];
    for (int nt = 0; nt < 4; nt++)
      pkv[nt] = *reinterpret_cast<const short4v*>(pkrow + key0 + nt * 16 + quad * 4);

    // V A-frags (16x16x16): A[i=d][k=quad*4+r], contiguous along key
    short4v vf[4][4];
    for (int dt = 0; dt < 4; dt++)
      for (int nt = 0; nt < 4; nt++)
        vf[dt][nt] = *reinterpret_cast<const short4v*>(
            vbase + (size_t)(dt * 16 + l15) * LK + key0 + nt * 16 + quad * 4);

    // prefetch next chunk's K frags (hidden behind exp + PV)
    if (kc + 1 < 8) {
      for (int nt = 0; nt < 4; nt++)
        for (int ks = 0; ks < 2; ks++)
          kf[nt][ks] = *reinterpret_cast<const short8*>(
              kbase + (size_t)(key0 + 64 + nt * 16 + l15) * DK + ks * 32 + quad * 8);
    }

    // pin: all loads above stay above; exp/PV consumers below
    __builtin_amdgcn_sched_barrier(0);

    // exp + in-register pack into PV B-frags
    short4v pf[4];
    for (int nt = 0; nt < 4; nt++) {
      float p[4];
      for (int r = 0; r < 4; r++) {
        int pv = pkv[nt][r];
        float t = fmaf(sa[nt][r], 0.125f, bts[pv < 0 ? 0 : pv]);
        t = (pv < 0) ? -1e9f : t;
        p[r] = __expf(t);
      }
      denom += (p[0] + p[1]) + (p[2] + p[3]);
      short4v pk4;
      for (int r = 0; r < 4; r++) {
        bf16 tb = __float2bfloat16(p[r]);
        pk4[r] = *reinterpret_cast<short*>(&tb);
      }
      pf[nt] = pk4;
    }

    // PV: O^T[d][q] += sum_key V[d][key] * P^T[key][q]
    for (int dt = 0; dt < 4; dt++)
      for (int nt = 0; nt < 4; nt++)
        of[dt] = __builtin_amdgcn_mfma_f32_16x16x16bf16_1k(vf[dt][nt], pf[nt], of[dt], 0, 0, 0);
  }

  // cross-quad reduction of the denominator (keys split across quads)
  denom += __shfl_xor(denom, 16, 64);
  denom += __shfl_xor(denom, 32, 64);

  size_t rowi = ((size_t)z * 64 + bh) * LQ + q;
  float* orow = Opart + rowi * 64;
  for (int dt = 0; dt < 4; dt++)
    *reinterpret_cast<f32x4*>(orow + dt * 16 + quad * 4) = of[dt];
  if (quad == 0) L[rowi] = denom;
}

// combine the four split-K partials -> bf16 Ob (plain sums; same fixed shift)
__global__ __launch_bounds__(256) void attn_combine(const float* __restrict__ Opart,
                                                    const float* __restrict__ L,
                                                    bf16* __restrict__ Ob) {
  int t = blockIdx.x * 256 + threadIdx.x;  // over 2M/4
  int g = t * 4;
  int row = g >> 6, d0 = g & 63;
  float l = L[row] + L[32768 + row] + L[65536 + row] + L[98304 + row];
  float4 o = {0.f, 0.f, 0.f, 0.f};
  for (int z = 0; z < 4; z++) {
    float4 p = *reinterpret_cast<const float4*>(Opart + (((size_t)z * 32768 + row) << 6) + d0);
    o.x += p.x; o.y += p.y; o.z += p.z; o.w += p.w;
  }
  float inv = 1.f / l;
  bf16 t0 = __float2bfloat16(o.x * inv), t1 = __float2bfloat16(o.y * inv);
  bf16 t2 = __float2bfloat16(o.z * inv), t3 = __float2bfloat16(o.w * inv);
  short4 pk;
  pk.x = *reinterpret_cast<short*>(&t0);
  pk.y = *reinterpret_cast<short*>(&t1);
  pk.z = *reinterpret_cast<short*>(&t2);
  pk.w = *reinterpret_cast<short*>(&t3);
  int bh = row >> 9, qq = row & 511, b_ = bh >> 4, h = bh & 15;
  *reinterpret_cast<short4*>(Ob + ((size_t)(b_ * LQ + qq)) * DM + h * 64 + d0) = pk;
}

// ---------------- launcher ----------------

extern "C" void kernel_launch(void* const* d_in, const int* in_sizes, int n_in,
                              void* d_out, int out_size, void* d_ws, size_t ws_size,
                              hipStream_t stream) {
  const float* q = (const float*)d_in[0];
  const float* k = (const float*)d_in[1];
  const float* v = (const float*)d_in[2];
  const int* bidx = (const int*)d_in[3];
  const int* mask = (const int*)d_in[4];
  const float* Wq = (const float*)d_in[5];
  const float* bq = (const float*)d_in[6];
  const float* Wk = (const float*)d_in[7];
  const float* bk = (const float*)d_in[8];
  const float* Wv = (const float*)d_in[9];
  const float* bv = (const float*)d_in[10];
  const float* Wo = (const float*)d_in[11];
  const float* bo = (const float*)d_in[12];
  const float* btab = (const float*)d_in[13];

  char* ws = (char*)d_ws;
  bf16* qb  = (bf16*)(ws + 0);
  bf16* kb  = (bf16*)(ws + 4194304);
  bf16* vb  = (bf16*)(ws + 20971520);
  bf16* Wqb = (bf16*)(ws + 37748736);
  bf16* Wkb = (bf16*)(ws + 39845888);
  bf16* Wvb = (bf16*)(ws + 41943040);
  bf16* Wob = (bf16*)(ws + 44040192);
  bf16* Qh  = (bf16*)(ws + 46137344);
  bf16* Kh  = (bf16*)(ws + 50331648);
  bf16* Vt  = (bf16*)(ws + 67108864);
  short* pkd = (short*)(ws + 83886080);
  bf16* Ob  = (bf16*)(ws + 92274688);
  // btabT overlays the START of the Ob region: written by fused_cvt, read by
  // attn4, and only THEN overwritten by attn_combine (stream-ordered — safe).
  float* btabT = (float*)(ws + 92274688);      // 57,600 B
  // Opart/L overlay qb/kb/vb region (dead after the projection GEMMs)
  float* Opart = (float*)(ws + 0);             // 33,554,432 B
  float* L     = (float*)(ws + 33554432);      //    524,288 B
  (void)ws_size; (void)in_sizes; (void)n_in; (void)out_size;

  hipLaunchKernelGGL(fused_cvt, dim3(26625), dim3(256), 0, stream,
                     q, k, v, bidx, mask, Wq, Wk, Wv, Wo, btab,
                     qb, kb, vb, Wqb, Wkb, Wvb, Wob, pkd, btabT);

  hipLaunchKernelGGL((gemm_bt<0, 64>), dim3(32, 8), dim3(256), 0, stream,
                     qb, Wqb, bq, (void*)Qh, 2048, 1024, 1024, LQ);
  hipLaunchKernelGGL((gemm_bt<0, 128>), dim3(64, 8), dim3(256), 0, stream,
                     kb, Wkb, bk, (void*)Kh, 8192, 1024, 1024, LK);
  hipLaunchKernelGGL((gemm_bt<1, 128>), dim3(64, 8), dim3(256), 0, stream,
                     vb, Wvb, bv, (void*)Vt, 8192, 1024, 1024, LK);

  hipLaunchKernelGGL(attn4, dim3(BSZ * H, LQ / 64, 4), dim3(256), 0, stream,
                     Qh, Kh, Vt, pkd, btabT, Opart, L);
  hipLaunchKernelGGL(attn_combine, dim3(2048), dim3(256), 0, stream,
                     Opart, L, Ob);

  hipLaunchKernelGGL((gemm_bt<2, 64>), dim3(32, 8), dim3(256), 0, stream,
                     Ob, Wob, bo, d_out, 2048, 1024, 1024, LQ);
}

// Round 8
// 343.996 us; speedup vs baseline: 1.3807x; 1.3807x over previous
//
#include <hip/hip_runtime.h>
#include <hip/hip_bf16.h>

#define H 16
#define DK 64
#define DM 1024
#define LQ 512
#define LK 2048
#define BSZ 4

typedef __hip_bfloat16 bf16;
typedef __attribute__((ext_vector_type(8))) short short8;
typedef __attribute__((ext_vector_type(4))) short short4v;
typedef __attribute__((ext_vector_type(4))) float f32x4;

// ---------------- fused converts: q,k,v,Wq,Wk,Wv,Wo -> bf16; pack bias/mask; btabT ----------------

__global__ __launch_bounds__(256) void fused_cvt(
    const float* __restrict__ q, const float* __restrict__ k, const float* __restrict__ v,
    const int* __restrict__ bidx, const int* __restrict__ msk,
    const float* __restrict__ Wq, const float* __restrict__ Wk,
    const float* __restrict__ Wv, const float* __restrict__ Wo,
    const float* __restrict__ btab,
    bf16* __restrict__ qb, bf16* __restrict__ kb, bf16* __restrict__ vb,
    bf16* __restrict__ Wqb, bf16* __restrict__ Wkb, bf16* __restrict__ Wvb,
    bf16* __restrict__ Wob, short* __restrict__ pkd, float* __restrict__ btabT) {
  const int blk = blockIdx.x, tid = threadIdx.x;
  const float* src;
  bf16* dst;
  int base;
  if (blk < 2048)       { src = q;  dst = qb;  base = blk; }
  else if (blk < 10240) { src = k;  dst = kb;  base = blk - 2048; }
  else if (blk < 18432) { src = v;  dst = vb;  base = blk - 10240; }
  else if (blk < 19456) { src = Wq; dst = Wqb; base = blk - 18432; }
  else if (blk < 20480) { src = Wk; dst = Wkb; base = blk - 19456; }
  else if (blk < 21504) { src = Wv; dst = Wvb; base = blk - 20480; }
  else if (blk < 22528) { src = Wo; dst = Wob; base = blk - 21504; }
  else if (blk < 26624) {
    int i = (blk - 22528) * 1024 + tid * 4;
    int4 a = *reinterpret_cast<const int4*>(bidx + i);
    int4 m = *reinterpret_cast<const int4*>(msk + i);
    short4 r;
    r.x = m.x ? (short)a.x : (short)-1;
    r.y = m.y ? (short)a.y : (short)-1;
    r.z = m.z ? (short)a.z : (short)-1;
    r.w = m.w ? (short)a.w : (short)-1;
    *reinterpret_cast<short4*>(pkd + i) = r;
    return;
  } else {
    // bias table: transpose + fold the fixed softmax shift (-10)
    for (int j = tid; j < 900 * H; j += 256) {
      int hh = j / 900, i = j - hh * 900;
      btabT[hh * 900 + i] = btab[i * H + hh] - 10.0f;
    }
    return;
  }
  int i = base * 1024 + tid * 4;
  float4 val = *reinterpret_cast<const float4*>(src + i);
  bf16 o0 = __float2bfloat16(val.x), o1 = __float2bfloat16(val.y);
  bf16 o2 = __float2bfloat16(val.z), o3 = __float2bfloat16(val.w);
  short4 pk;
  pk.x = *reinterpret_cast<short*>(&o0);
  pk.y = *reinterpret_cast<short*>(&o1);
  pk.z = *reinterpret_cast<short*>(&o2);
  pk.w = *reinterpret_cast<short*>(&o3);
  *reinterpret_cast<short4*>(reinterpret_cast<short*>(dst) + i) = pk;
}

// ---------------- GEMM: C[m][n] = sum_k A[m][k]*B[n][k] + bias[n] ----------------
// MODE 0: write bf16 head-interleaved  dst[((b*H+h)*Lrows + l)*64 + d]
// MODE 1: write bf16 d-major V        dst[((b*H+h)*64 + d)*LK + key]
// MODE 2: write f32 row-major          dst[row*N + col]
// TM: 128 (4 waves as 2x2, 64x64 each) or 64 (4 waves as 1x4, 64x32 each)

__device__ __forceinline__ void g2lds16(const bf16* g, bf16* l) {
  __builtin_amdgcn_global_load_lds(
      (__attribute__((address_space(1))) void*)(g),
      (__attribute__((address_space(3))) void*)(l), 16, 0, 0);
}

template <int MODE, int TM>
__global__ __launch_bounds__(256) void gemm_bt(const bf16* __restrict__ A,
                                               const bf16* __restrict__ B,
                                               const float* __restrict__ bias,
                                               void* __restrict__ out,
                                               int M, int N, int K, int Lrows) {
  __shared__ bf16 As[TM * 32];
  __shared__ bf16 Bs[128 * 32];
  constexpr int NT = (TM == 128) ? 4 : 2;
  const int tid = threadIdx.x;
  const int wave = tid >> 6, lane = tid & 63;
  const int quad = lane >> 4, l15 = lane & 15;
  const int rowbase = (TM == 128) ? (wave >> 1) * 64 : 0;
  const int colbase = (TM == 128) ? (wave & 1) * 64 : wave * 32;
  const int rowA0 = blockIdx.x * TM, colB0 = blockIdx.y * 128;
  const int srow = lane >> 2, skq = lane & 3;

  f32x4 acc[4][NT];
  const f32x4 zero = {0.f, 0.f, 0.f, 0.f};
  for (int mt = 0; mt < 4; mt++)
    for (int nt = 0; nt < NT; nt++) acc[mt][nt] = zero;

  for (int k0 = 0; k0 < K; k0 += 32) {
    if (TM == 128) {
      for (int c = 0; c < 2; ++c) {
        int r = wave * 32 + c * 16;
        g2lds16(A + (size_t)(rowA0 + r + srow) * K + k0 + skq * 8, As + r * 32);
      }
    } else {
      int r = wave * 16;
      g2lds16(A + (size_t)(rowA0 + r + srow) * K + k0 + skq * 8, As + r * 32);
    }
    for (int c = 0; c < 2; ++c) {
      int r = wave * 32 + c * 16;
      g2lds16(B + (size_t)(colB0 + r + srow) * K + k0 + skq * 8, Bs + r * 32);
    }
    __syncthreads();
    short8 af[4], bfr[NT];
    for (int mt = 0; mt < 4; mt++)
      af[mt] = *reinterpret_cast<const short8*>(As + (rowbase + mt * 16 + l15) * 32 + quad * 8);
    for (int nt = 0; nt < NT; nt++)
      bfr[nt] = *reinterpret_cast<const short8*>(Bs + (colbase + nt * 16 + l15) * 32 + quad * 8);
    for (int mt = 0; mt < 4; mt++)
      for (int nt = 0; nt < NT; nt++)
        acc[mt][nt] = __builtin_amdgcn_mfma_f32_16x16x32_bf16(af[mt], bfr[nt], acc[mt][nt], 0, 0, 0);
    __syncthreads();
  }

  const int bb = (MODE == 2) ? 0 : (rowA0 / Lrows);
  const int lb = (MODE == 2) ? rowA0 : (rowA0 - bb * Lrows);
  for (int nt = 0; nt < NT; nt++) {
    int col = colB0 + colbase + nt * 16 + l15;
    float bv = bias[col];
    int hh = col >> 6, d = col & 63;
    for (int mt = 0; mt < 4; mt++) {
      int lrow0 = lb + rowbase + mt * 16 + quad * 4;
      f32x4 v = acc[mt][nt];
      if (MODE == 1) {
        short4 pkv;
        bf16 t0 = __float2bfloat16(v[0] + bv);
        bf16 t1 = __float2bfloat16(v[1] + bv);
        bf16 t2 = __float2bfloat16(v[2] + bv);
        bf16 t3 = __float2bfloat16(v[3] + bv);
        pkv.x = *reinterpret_cast<short*>(&t0);
        pkv.y = *reinterpret_cast<short*>(&t1);
        pkv.z = *reinterpret_cast<short*>(&t2);
        pkv.w = *reinterpret_cast<short*>(&t3);
        *reinterpret_cast<short4*>((bf16*)out +
            ((size_t)((bb * H + hh) * DK + d)) * LK + lrow0) = pkv;
      } else {
        for (int r = 0; r < 4; r++) {
          float val = v[r] + bv;
          if (MODE == 0) {
            ((bf16*)out)[(((size_t)(bb * H + hh) * Lrows + lrow0 + r) << 6) + d] = __float2bfloat16(val);
          } else {
            ((float*)out)[(size_t)(lrow0 + r) * N + col] = val;
          }
        }
      }
    }
  }
}

// ---------------- attention v6: LDS-staged K/V (m97 pattern) + S^T reg-P ----------------
// grid (BSZ*H, LQ/64, 2), block 256. Block = (bh, 64 q rows, 1024 keys, 16 chunks).
// K/V chunks staged via global_load_lds (16B/lane DMA), double-buffered, ONE barrier
// per chunk. Lane-linear LDS layout forced by the DMA -> XOR-swizzle the global
// source segment (seg_lds = (seg_glob + row) & 7) so column-ish reads avoid
// 16-way bank conflicts (K reads 2-way=free, V reads <=4-way).
// Math identical to HW-verified attn4: S^T=MFMA(A=K,B=Q) C-layout == 16x16x16
// B-operand layout -> exp(P) packs in-register; PV: O^T = V(A) x P^T(B).
// p = exp(s/8 + bias - 10), masked -> 0; z-halves sum linearly (fixed shift).

__global__ __launch_bounds__(256) void attn6(const bf16* __restrict__ Qh,
                                             const bf16* __restrict__ Kh,
                                             const bf16* __restrict__ Vt,
                                             const short* __restrict__ pkm,
                                             const float* __restrict__ btabT,
                                             float* __restrict__ Opart,
                                             float* __restrict__ L) {
  __shared__ __align__(16) bf16 Kbuf[2][64 * 64];
  __shared__ __align__(16) bf16 Vbuf[2][64 * 64];
  __shared__ float bts[900];
  const int tid = threadIdx.x;
  const int wave = tid >> 6, lane = tid & 63;
  const int quad = lane >> 4, l15 = lane & 15;
  const int bh = blockIdx.x, b = bh >> 4, h = bh & 15;
  const int qt = blockIdx.y, z = blockIdx.z;
  const int key_base = z * 1024;

  for (int i = tid; i < 900; i += 256) bts[i] = btabT[h * 900 + i];

  const int q = qt * 64 + wave * 16 + l15;  // this lane's q (B-operand col)
  short8 qf[2];
  for (int ks = 0; ks < 2; ks++)
    qf[ks] = *reinterpret_cast<const short8*>(
        Qh + ((size_t)bh * LQ + q) * DK + ks * 32 + quad * 8);

  const bf16* kbase = Kh + ((size_t)bh * LK + key_base) * DK;
  const bf16* vbase = Vt + ((size_t)bh * DK) * LK + key_base;
  const short* pkrow = pkm + ((size_t)b * LQ + q) * LK + key_base;

  // staging geometry (per wave, 2 insts each for K and V):
  // inst c, lane i -> LDS row w*16 + c*8 + (i>>3), seg i&7 (lane-linear DMA);
  // row's global seg g = ((i&7) - (i>>3)) & 7   (XOR/rotate swizzle, row%8 = i>>3)
  const int srow_off = lane >> 3;              // 0..7
  const int sseg = ((lane & 7) - srow_off) & 7;  // global segment to fetch

  f32x4 of[4];
  float denom = 0.f;
  const f32x4 zero = {0.f, 0.f, 0.f, 0.f};
  for (int dt = 0; dt < 4; dt++) of[dt] = zero;

  // ---- prologue: stage chunk 0 into buf0, prefetch pk chunk 0 ----
  for (int c = 0; c < 2; c++) {
    int row = wave * 16 + c * 8 + srow_off;
    g2lds16(kbase + (size_t)row * DK + sseg * 8,
            &Kbuf[0][(wave * 16 + c * 8) * 64]);
    g2lds16(vbase + (size_t)row * LK + sseg * 8,
            &Vbuf[0][(wave * 16 + c * 8) * 64]);
  }
  short4v pkv[4];
  for (int nt = 0; nt < 4; nt++)
    pkv[nt] = *reinterpret_cast<const short4v*>(pkrow + nt * 16 + quad * 4);

  __syncthreads();

  for (int kc = 0; kc < 16; ++kc) {
    const int buf = kc & 1;

    // stage chunk kc+1 into buf^1 (completes at the end-of-iter barrier)
    short4v pk_n[4];
    if (kc < 15) {
      const int key1 = (kc + 1) * 64;
      for (int c = 0; c < 2; c++) {
        int row = wave * 16 + c * 8 + srow_off;
        g2lds16(kbase + (size_t)(key1 + row) * DK + sseg * 8,
                &Kbuf[buf ^ 1][(wave * 16 + c * 8) * 64]);
        g2lds16(vbase + (size_t)row * LK + key1 + sseg * 8,
                &Vbuf[buf ^ 1][(wave * 16 + c * 8) * 64]);
      }
      for (int nt = 0; nt < 4; nt++)
        pk_n[nt] = *reinterpret_cast<const short4v*>(pkrow + key1 + nt * 16 + quad * 4);
    }

    // K frags from LDS (swizzled): row = nt*16+l15, global seg ks*4+quad
    // at LDS seg (ks*4+quad+l15)&7  -> 2-way conflicts only
    f32x4 sa[4];
    for (int nt = 0; nt < 4; nt++) sa[nt] = zero;
    for (int nt = 0; nt < 4; nt++)
      for (int ks = 0; ks < 2; ks++) {
        short8 kf = *reinterpret_cast<const short8*>(
            &Kbuf[buf][(nt * 16 + l15) * 64 + (((ks * 4 + quad + l15) & 7) << 3)]);
        sa[nt] = __builtin_amdgcn_mfma_f32_16x16x32_bf16(kf, qf[ks], sa[nt], 0, 0, 0);
      }

    // V frags from LDS (swizzled): row d = dt*16+l15, global seg nt*2+(quad>>1),
    // sub-offset (quad&1)*4 elems -> LDS seg (nt*2+(quad>>1)+l15)&7
    short4v vf[4][4];
    for (int dt = 0; dt < 4; dt++)
      for (int nt = 0; nt < 4; nt++)
        vf[dt][nt] = *reinterpret_cast<const short4v*>(
            &Vbuf[buf][(dt * 16 + l15) * 64 +
                       (((nt * 2 + (quad >> 1) + l15) & 7) << 3) + ((quad & 1) << 2)]);

    // exp + in-register pack into PV B-frags
    short4v pf[4];
    for (int nt = 0; nt < 4; nt++) {
      float p[4];
      for (int r = 0; r < 4; r++) {
        int pv = pkv[nt][r];
        float t = fmaf(sa[nt][r], 0.125f, bts[pv < 0 ? 0 : pv]);
        t = (pv < 0) ? -1e9f : t;
        p[r] = __expf(t);
      }
      denom += (p[0] + p[1]) + (p[2] + p[3]);
      short4v pk4;
      for (int r = 0; r < 4; r++) {
        bf16 tb = __float2bfloat16(p[r]);
        pk4[r] = *reinterpret_cast<short*>(&tb);
      }
      pf[nt] = pk4;
    }

    // PV: O^T[d][q] += V[d][key] * P^T[key][q]
    for (int dt = 0; dt < 4; dt++)
      for (int nt = 0; nt < 4; nt++)
        of[dt] = __builtin_amdgcn_mfma_f32_16x16x16bf16_1k(vf[dt][nt], pf[nt], of[dt], 0, 0, 0);

    if (kc < 15)
      for (int nt = 0; nt < 4; nt++) pkv[nt] = pk_n[nt];

    __syncthreads();  // staging of buf^1 complete; all reads of buf done
  }

  // cross-quad reduction of the denominator (keys split across quads)
  denom += __shfl_xor(denom, 16, 64);
  denom += __shfl_xor(denom, 32, 64);

  size_t rowi = ((size_t)z * 64 + bh) * LQ + q;
  float* orow = Opart + rowi * 64;
  for (int dt = 0; dt < 4; dt++)
    *reinterpret_cast<f32x4*>(orow + dt * 16 + quad * 4) = of[dt];
  if (quad == 0) L[rowi] = denom;
}

// combine the two split-K halves -> bf16 Ob (plain sums; same fixed shift)
__global__ __launch_bounds__(256) void attn_combine(const float* __restrict__ Opart,
                                                    const float* __restrict__ L,
                                                    bf16* __restrict__ Ob) {
  int t = blockIdx.x * 256 + threadIdx.x;  // over 2M/4
  int g = t * 4;
  int row = g >> 6, d0 = g & 63;
  float l = L[row] + L[32768 + row];
  float4 o;
  float4 p0 = *reinterpret_cast<const float4*>(Opart + ((size_t)row << 6) + d0);
  float4 p1 = *reinterpret_cast<const float4*>(Opart + (((size_t)32768 + row) << 6) + d0);
  o.x = p0.x + p1.x; o.y = p0.y + p1.y; o.z = p0.z + p1.z; o.w = p0.w + p1.w;
  float inv = 1.f / l;
  bf16 t0 = __float2bfloat16(o.x * inv), t1 = __float2bfloat16(o.y * inv);
  bf16 t2 = __float2bfloat16(o.z * inv), t3 = __float2bfloat16(o.w * inv);
  short4 pk;
  pk.x = *reinterpret_cast<short*>(&t0);
  pk.y = *reinterpret_cast<short*>(&t1);
  pk.z = *reinterpret_cast<short*>(&t2);
  pk.w = *reinterpret_cast<short*>(&t3);
  int bh = row >> 9, qq = row & 511, b_ = bh >> 4, h = bh & 15;
  *reinterpret_cast<short4*>(Ob + ((size_t)(b_ * LQ + qq)) * DM + h * 64 + d0) = pk;
}

// ---------------- launcher ----------------

extern "C" void kernel_launch(void* const* d_in, const int* in_sizes, int n_in,
                              void* d_out, int out_size, void* d_ws, size_t ws_size,
                              hipStream_t stream) {
  const float* q = (const float*)d_in[0];
  const float* k = (const float*)d_in[1];
  const float* v = (const float*)d_in[2];
  const int* bidx = (const int*)d_in[3];
  const int* mask = (const int*)d_in[4];
  const float* Wq = (const float*)d_in[5];
  const float* bq = (const float*)d_in[6];
  const float* Wk = (const float*)d_in[7];
  const float* bk = (const float*)d_in[8];
  const float* Wv = (const float*)d_in[9];
  const float* bv = (const float*)d_in[10];
  const float* Wo = (const float*)d_in[11];
  const float* bo = (const float*)d_in[12];
  const float* btab = (const float*)d_in[13];

  char* ws = (char*)d_ws;
  bf16* qb  = (bf16*)(ws + 0);
  bf16* kb  = (bf16*)(ws + 4194304);
  bf16* vb  = (bf16*)(ws + 20971520);
  bf16* Wqb = (bf16*)(ws + 37748736);
  bf16* Wkb = (bf16*)(ws + 39845888);
  bf16* Wvb = (bf16*)(ws + 41943040);
  bf16* Wob = (bf16*)(ws + 44040192);
  bf16* Qh  = (bf16*)(ws + 46137344);
  bf16* Kh  = (bf16*)(ws + 50331648);
  bf16* Vt  = (bf16*)(ws + 67108864);
  short* pkd = (short*)(ws + 83886080);
  bf16* Ob  = (bf16*)(ws + 92274688);
  // btabT overlays the START of the Ob region: written by fused_cvt, read by
  // attn6, and only THEN overwritten by attn_combine (stream-ordered — safe).
  float* btabT = (float*)(ws + 92274688);      // 57,600 B
  // Opart/L overlay qb/kb region (dead after the projection GEMMs)
  float* Opart = (float*)(ws + 0);             // 16,777,216 B (2 z-halves)
  float* L     = (float*)(ws + 16777216);      //    262,144 B
  (void)ws_size; (void)in_sizes; (void)n_in; (void)out_size;

  hipLaunchKernelGGL(fused_cvt, dim3(26625), dim3(256), 0, stream,
                     q, k, v, bidx, mask, Wq, Wk, Wv, Wo, btab,
                     qb, kb, vb, Wqb, Wkb, Wvb, Wob, pkd, btabT);

  hipLaunchKernelGGL((gemm_bt<0, 64>), dim3(32, 8), dim3(256), 0, stream,
                     qb, Wqb, bq, (void*)Qh, 2048, 1024, 1024, LQ);
  hipLaunchKernelGGL((gemm_bt<0, 128>), dim3(64, 8), dim3(256), 0, stream,
                     kb, Wkb, bk, (void*)Kh, 8192, 1024, 1024, LK);
  hipLaunchKernelGGL((gemm_bt<1, 128>), dim3(64, 8), dim3(256), 0, stream,
                     vb, Wvb, bv, (void*)Vt, 8192, 1024, 1024, LK);

  hipLaunchKernelGGL(attn6, dim3(BSZ * H, LQ / 64, 2), dim3(256), 0, stream,
                     Qh, Kh, Vt, pkd, btabT, Opart, L);
  hipLaunchKernelGGL(attn_combine, dim3(2048), dim3(256), 0, stream,
                     Opart, L, Ob);

  hipLaunchKernelGGL((gemm_bt<2, 64>), dim3(32, 8), dim3(256), 0, stream,
                     Ob, Wob, bo, d_out, 2048, 1024, 1024, LQ);
}

// Round 9
// 338.773 us; speedup vs baseline: 1.4020x; 1.0154x over previous
//
#include <hip/hip_runtime.h>
#include <hip/hip_bf16.h>

#define H 16
#define DK 64
#define DM 1024
#define LQ 512
#define LK 2048
#define BSZ 4

typedef __hip_bfloat16 bf16;
typedef __attribute__((ext_vector_type(8))) short short8;
typedef __attribute__((ext_vector_type(4))) short short4v;
typedef __attribute__((ext_vector_type(4))) float f32x4;

// ---------------- fused converts: q,k,v,Wq,Wk,Wv,Wo -> bf16; pack bias/mask; btabT ----------------

__global__ __launch_bounds__(256) void fused_cvt(
    const float* __restrict__ q, const float* __restrict__ k, const float* __restrict__ v,
    const int* __restrict__ bidx, const int* __restrict__ msk,
    const float* __restrict__ Wq, const float* __restrict__ Wk,
    const float* __restrict__ Wv, const float* __restrict__ Wo,
    const float* __restrict__ btab,
    bf16* __restrict__ qb, bf16* __restrict__ kb, bf16* __restrict__ vb,
    bf16* __restrict__ Wqb, bf16* __restrict__ Wkb, bf16* __restrict__ Wvb,
    bf16* __restrict__ Wob, short* __restrict__ pkd, float* __restrict__ btabT) {
  const int blk = blockIdx.x, tid = threadIdx.x;
  const float* src;
  bf16* dst;
  int base;
  if (blk < 2048)       { src = q;  dst = qb;  base = blk; }
  else if (blk < 10240) { src = k;  dst = kb;  base = blk - 2048; }
  else if (blk < 18432) { src = v;  dst = vb;  base = blk - 10240; }
  else if (blk < 19456) { src = Wq; dst = Wqb; base = blk - 18432; }
  else if (blk < 20480) { src = Wk; dst = Wkb; base = blk - 19456; }
  else if (blk < 21504) { src = Wv; dst = Wvb; base = blk - 20480; }
  else if (blk < 22528) { src = Wo; dst = Wob; base = blk - 21504; }
  else if (blk < 26624) {
    int i = (blk - 22528) * 1024 + tid * 4;
    int4 a = *reinterpret_cast<const int4*>(bidx + i);
    int4 m = *reinterpret_cast<const int4*>(msk + i);
    short4 r;
    r.x = m.x ? (short)a.x : (short)-1;
    r.y = m.y ? (short)a.y : (short)-1;
    r.z = m.z ? (short)a.z : (short)-1;
    r.w = m.w ? (short)a.w : (short)-1;
    *reinterpret_cast<short4*>(pkd + i) = r;
    return;
  } else {
    // bias table: transpose + fold the fixed softmax shift (-10)
    for (int j = tid; j < 900 * H; j += 256) {
      int hh = j / 900, i = j - hh * 900;
      btabT[hh * 900 + i] = btab[i * H + hh] - 10.0f;
    }
    return;
  }
  int i = base * 1024 + tid * 4;
  float4 val = *reinterpret_cast<const float4*>(src + i);
  bf16 o0 = __float2bfloat16(val.x), o1 = __float2bfloat16(val.y);
  bf16 o2 = __float2bfloat16(val.z), o3 = __float2bfloat16(val.w);
  short4 pk;
  pk.x = *reinterpret_cast<short*>(&o0);
  pk.y = *reinterpret_cast<short*>(&o1);
  pk.z = *reinterpret_cast<short*>(&o2);
  pk.w = *reinterpret_cast<short*>(&o3);
  *reinterpret_cast<short4*>(reinterpret_cast<short*>(dst) + i) = pk;
}

// ---------------- GEMM: C[m][n] = sum_k A[m][k]*B[n][k] + bias[n] ----------------
// MODE 0: write bf16 head-interleaved  dst[((b*H+h)*Lrows + l)*64 + d]
// MODE 1: d-major V dst[((b*H+h)*64 + d)*LK + key] — computed TRANSPOSED in-register
//         (swapped MFMA operands: col=lane&15 -> key, row=quad*4+r -> d) so stores
//         are 32B-contiguous runs along key instead of 8B at 4KB stride.
// MODE 2: write f32 row-major          dst[row*N + col]
// TM: 128 (4 waves as 2x2, 64x64 each) or 64 (4 waves as 1x4, 64x32 each)

__device__ __forceinline__ void g2lds16(const bf16* g, bf16* l) {
  __builtin_amdgcn_global_load_lds(
      (__attribute__((address_space(1))) void*)(g),
      (__attribute__((address_space(3))) void*)(l), 16, 0, 0);
}

template <int MODE, int TM>
__global__ __launch_bounds__(256) void gemm_bt(const bf16* __restrict__ A,
                                               const bf16* __restrict__ B,
                                               const float* __restrict__ bias,
                                               void* __restrict__ out,
                                               int M, int N, int K, int Lrows) {
  __shared__ bf16 As[TM * 32];
  __shared__ bf16 Bs[128 * 32];
  constexpr int NT = (TM == 128) ? 4 : 2;
  const int tid = threadIdx.x;
  const int wave = tid >> 6, lane = tid & 63;
  const int quad = lane >> 4, l15 = lane & 15;
  const int rowbase = (TM == 128) ? (wave >> 1) * 64 : 0;
  const int colbase = (TM == 128) ? (wave & 1) * 64 : wave * 32;
  const int rowA0 = blockIdx.x * TM, colB0 = blockIdx.y * 128;
  const int srow = lane >> 2, skq = lane & 3;

  f32x4 acc[4][NT];
  const f32x4 zero = {0.f, 0.f, 0.f, 0.f};
  for (int mt = 0; mt < 4; mt++)
    for (int nt = 0; nt < NT; nt++) acc[mt][nt] = zero;

  for (int k0 = 0; k0 < K; k0 += 32) {
    if (TM == 128) {
      for (int c = 0; c < 2; ++c) {
        int r = wave * 32 + c * 16;
        g2lds16(A + (size_t)(rowA0 + r + srow) * K + k0 + skq * 8, As + r * 32);
      }
    } else {
      int r = wave * 16;
      g2lds16(A + (size_t)(rowA0 + r + srow) * K + k0 + skq * 8, As + r * 32);
    }
    for (int c = 0; c < 2; ++c) {
      int r = wave * 32 + c * 16;
      g2lds16(B + (size_t)(colB0 + r + srow) * K + k0 + skq * 8, Bs + r * 32);
    }
    __syncthreads();
    short8 af[4], bfr[NT];
    for (int mt = 0; mt < 4; mt++)
      af[mt] = *reinterpret_cast<const short8*>(As + (rowbase + mt * 16 + l15) * 32 + quad * 8);
    for (int nt = 0; nt < NT; nt++)
      bfr[nt] = *reinterpret_cast<const short8*>(Bs + (colbase + nt * 16 + l15) * 32 + quad * 8);
    for (int mt = 0; mt < 4; mt++)
      for (int nt = 0; nt < NT; nt++) {
        if (MODE == 1)  // swapped: A-op = W rows (n), B-op = act rows (m=key)
          acc[mt][nt] = __builtin_amdgcn_mfma_f32_16x16x32_bf16(bfr[nt], af[mt], acc[mt][nt], 0, 0, 0);
        else
          acc[mt][nt] = __builtin_amdgcn_mfma_f32_16x16x32_bf16(af[mt], bfr[nt], acc[mt][nt], 0, 0, 0);
      }
    __syncthreads();
  }

  const int bb = (MODE == 2) ? 0 : (rowA0 / Lrows);
  const int lb = (MODE == 2) ? rowA0 : (rowA0 - bb * Lrows);
  if (MODE == 1) {
    // D[row=quad*4+r -> n(d-col)][col=l15 -> m(key)]
    for (int mt = 0; mt < 4; mt++) {
      int key = lb + rowbase + mt * 16 + l15;
      for (int nt = 0; nt < NT; nt++) {
        f32x4 v = acc[mt][nt];
        for (int r = 0; r < 4; r++) {
          int ncol = colB0 + colbase + nt * 16 + quad * 4 + r;
          float bv = bias[ncol];
          int hh = ncol >> 6, d = ncol & 63;
          ((bf16*)out)[((size_t)((bb * H + hh) * DK + d)) * LK + key] =
              __float2bfloat16(v[r] + bv);
        }
      }
    }
    return;
  }
  for (int nt = 0; nt < NT; nt++) {
    int col = colB0 + colbase + nt * 16 + l15;
    float bv = bias[col];
    int hh = col >> 6, d = col & 63;
    for (int mt = 0; mt < 4; mt++) {
      int lrow0 = lb + rowbase + mt * 16 + quad * 4;
      f32x4 v = acc[mt][nt];
      for (int r = 0; r < 4; r++) {
        float val = v[r] + bv;
        if (MODE == 0) {
          ((bf16*)out)[(((size_t)(bb * H + hh) * Lrows + lrow0 + r) << 6) + d] = __float2bfloat16(val);
        } else {
          ((float*)out)[(size_t)(lrow0 + r) * N + col] = val;
        }
      }
    }
  }
}

// ---------------- attention v6: LDS-staged K/V (m97 pattern) + S^T reg-P ----------------
// grid (BSZ*H, LQ/64, 2), block 256. Block = (bh, 64 q rows, 1024 keys, 16 chunks).
// K/V chunks staged via global_load_lds (16B/lane DMA), double-buffered, ONE barrier
// per chunk. Lane-linear LDS layout forced by the DMA -> XOR-swizzle the global
// source segment (seg_lds = (seg_glob + row) & 7) so column-ish reads avoid
// 16-way bank conflicts (K reads 2-way=free, V reads <=4-way).
// Math identical to HW-verified attn4: S^T=MFMA(A=K,B=Q) C-layout == 16x16x16
// B-operand layout -> exp(P) packs in-register; PV: O^T = V(A) x P^T(B).
// p = exp(s/8 + bias - 10), masked -> 0; z-halves sum linearly (fixed shift).

__global__ __launch_bounds__(256) void attn6(const bf16* __restrict__ Qh,
                                             const bf16* __restrict__ Kh,
                                             const bf16* __restrict__ Vt,
                                             const short* __restrict__ pkm,
                                             const float* __restrict__ btabT,
                                             float* __restrict__ Opart,
                                             float* __restrict__ L) {
  __shared__ __align__(16) bf16 Kbuf[2][64 * 64];
  __shared__ __align__(16) bf16 Vbuf[2][64 * 64];
  __shared__ float bts[900];
  const int tid = threadIdx.x;
  const int wave = tid >> 6, lane = tid & 63;
  const int quad = lane >> 4, l15 = lane & 15;
  const int bh = blockIdx.x, b = bh >> 4, h = bh & 15;
  const int qt = blockIdx.y, z = blockIdx.z;
  const int key_base = z * 1024;

  for (int i = tid; i < 900; i += 256) bts[i] = btabT[h * 900 + i];

  const int q = qt * 64 + wave * 16 + l15;  // this lane's q (B-operand col)
  short8 qf[2];
  for (int ks = 0; ks < 2; ks++)
    qf[ks] = *reinterpret_cast<const short8*>(
        Qh + ((size_t)bh * LQ + q) * DK + ks * 32 + quad * 8);

  const bf16* kbase = Kh + ((size_t)bh * LK + key_base) * DK;
  const bf16* vbase = Vt + ((size_t)bh * DK) * LK + key_base;
  const short* pkrow = pkm + ((size_t)b * LQ + q) * LK + key_base;

  // staging geometry (per wave, 2 insts each for K and V):
  // inst c, lane i -> LDS row w*16 + c*8 + (i>>3), seg i&7 (lane-linear DMA);
  // row's global seg g = ((i&7) - (i>>3)) & 7   (rotate swizzle, row%8 = i>>3)
  const int srow_off = lane >> 3;              // 0..7
  const int sseg = ((lane & 7) - srow_off) & 7;  // global segment to fetch

  f32x4 of[4];
  float denom = 0.f;
  const f32x4 zero = {0.f, 0.f, 0.f, 0.f};
  for (int dt = 0; dt < 4; dt++) of[dt] = zero;

  // ---- prologue: stage chunk 0 into buf0, prefetch pk chunk 0 ----
  for (int c = 0; c < 2; c++) {
    int row = wave * 16 + c * 8 + srow_off;
    g2lds16(kbase + (size_t)row * DK + sseg * 8,
            &Kbuf[0][(wave * 16 + c * 8) * 64]);
    g2lds16(vbase + (size_t)row * LK + sseg * 8,
            &Vbuf[0][(wave * 16 + c * 8) * 64]);
  }
  short4v pkv[4];
  for (int nt = 0; nt < 4; nt++)
    pkv[nt] = *reinterpret_cast<const short4v*>(pkrow + nt * 16 + quad * 4);

  __syncthreads();

  for (int kc = 0; kc < 16; ++kc) {
    const int buf = kc & 1;

    // stage chunk kc+1 into buf^1 (completes at the end-of-iter barrier)
    short4v pk_n[4];
    if (kc < 15) {
      const int key1 = (kc + 1) * 64;
      for (int c = 0; c < 2; c++) {
        int row = wave * 16 + c * 8 + srow_off;
        g2lds16(kbase + (size_t)(key1 + row) * DK + sseg * 8,
                &Kbuf[buf ^ 1][(wave * 16 + c * 8) * 64]);
        g2lds16(vbase + (size_t)row * LK + key1 + sseg * 8,
                &Vbuf[buf ^ 1][(wave * 16 + c * 8) * 64]);
      }
      for (int nt = 0; nt < 4; nt++)
        pk_n[nt] = *reinterpret_cast<const short4v*>(pkrow + key1 + nt * 16 + quad * 4);
    }

    // K frags from LDS (swizzled): row = nt*16+l15, global seg ks*4+quad
    // at LDS seg (ks*4+quad+l15)&7
    f32x4 sa[4];
    for (int nt = 0; nt < 4; nt++) sa[nt] = zero;
    for (int nt = 0; nt < 4; nt++)
      for (int ks = 0; ks < 2; ks++) {
        short8 kf = *reinterpret_cast<const short8*>(
            &Kbuf[buf][(nt * 16 + l15) * 64 + (((ks * 4 + quad + l15) & 7) << 3)]);
        sa[nt] = __builtin_amdgcn_mfma_f32_16x16x32_bf16(kf, qf[ks], sa[nt], 0, 0, 0);
      }

    // V frags from LDS (swizzled): row d = dt*16+l15, global seg nt*2+(quad>>1),
    // sub-offset (quad&1)*4 elems -> LDS seg (nt*2+(quad>>1)+l15)&7
    short4v vf[4][4];
    for (int dt = 0; dt < 4; dt++)
      for (int nt = 0; nt < 4; nt++)
        vf[dt][nt] = *reinterpret_cast<const short4v*>(
            &Vbuf[buf][(dt * 16 + l15) * 64 +
                       (((nt * 2 + (quad >> 1) + l15) & 7) << 3) + ((quad & 1) << 2)]);

    // exp + in-register pack into PV B-frags
    short4v pf[4];
    for (int nt = 0; nt < 4; nt++) {
      float p[4];
      for (int r = 0; r < 4; r++) {
        int pv = pkv[nt][r];
        float t = fmaf(sa[nt][r], 0.125f, bts[pv < 0 ? 0 : pv]);
        t = (pv < 0) ? -1e9f : t;
        p[r] = __expf(t);
      }
      denom += (p[0] + p[1]) + (p[2] + p[3]);
      short4v pk4;
      for (int r = 0; r < 4; r++) {
        bf16 tb = __float2bfloat16(p[r]);
        pk4[r] = *reinterpret_cast<short*>(&tb);
      }
      pf[nt] = pk4;
    }

    // PV: O^T[d][q] += V[d][key] * P^T[key][q]
    for (int dt = 0; dt < 4; dt++)
      for (int nt = 0; nt < 4; nt++)
        of[dt] = __builtin_amdgcn_mfma_f32_16x16x16bf16_1k(vf[dt][nt], pf[nt], of[dt], 0, 0, 0);

    if (kc < 15)
      for (int nt = 0; nt < 4; nt++) pkv[nt] = pk_n[nt];

    __syncthreads();  // staging of buf^1 complete; all reads of buf done
  }

  // cross-quad reduction of the denominator (keys split across quads)
  denom += __shfl_xor(denom, 16, 64);
  denom += __shfl_xor(denom, 32, 64);

  size_t rowi = ((size_t)z * 64 + bh) * LQ + q;
  float* orow = Opart + rowi * 64;
  for (int dt = 0; dt < 4; dt++)
    *reinterpret_cast<f32x4*>(orow + dt * 16 + quad * 4) = of[dt];
  if (quad == 0) L[rowi] = denom;
}

// combine the two split-K halves -> bf16 Ob (plain sums; same fixed shift)
__global__ __launch_bounds__(256) void attn_combine(const float* __restrict__ Opart,
                                                    const float* __restrict__ L,
                                                    bf16* __restrict__ Ob) {
  int t = blockIdx.x * 256 + threadIdx.x;  // over 2M/4
  int g = t * 4;
  int row = g >> 6, d0 = g & 63;
  float l = L[row] + L[32768 + row];
  float4 o;
  float4 p0 = *reinterpret_cast<const float4*>(Opart + ((size_t)row << 6) + d0);
  float4 p1 = *reinterpret_cast<const float4*>(Opart + (((size_t)32768 + row) << 6) + d0);
  o.x = p0.x + p1.x; o.y = p0.y + p1.y; o.z = p0.z + p1.z; o.w = p0.w + p1.w;
  float inv = 1.f / l;
  bf16 t0 = __float2bfloat16(o.x * inv), t1 = __float2bfloat16(o.y * inv);
  bf16 t2 = __float2bfloat16(o.z * inv), t3 = __float2bfloat16(o.w * inv);
  short4 pk;
  pk.x = *reinterpret_cast<short*>(&t0);
  pk.y = *reinterpret_cast<short*>(&t1);
  pk.z = *reinterpret_cast<short*>(&t2);
  pk.w = *reinterpret_cast<short*>(&t3);
  int bh = row >> 9, qq = row & 511, b_ = bh >> 4, h = bh & 15;
  *reinterpret_cast<short4*>(Ob + ((size_t)(b_ * LQ + qq)) * DM + h * 64 + d0) = pk;
}

// ---------------- launcher ----------------

extern "C" void kernel_launch(void* const* d_in, const int* in_sizes, int n_in,
                              void* d_out, int out_size, void* d_ws, size_t ws_size,
                              hipStream_t stream) {
  const float* q = (const float*)d_in[0];
  const float* k = (const float*)d_in[1];
  const float* v = (const float*)d_in[2];
  const int* bidx = (const int*)d_in[3];
  const int* mask = (const int*)d_in[4];
  const float* Wq = (const float*)d_in[5];
  const float* bq = (const float*)d_in[6];
  const float* Wk = (const float*)d_in[7];
  const float* bk = (const float*)d_in[8];
  const float* Wv = (const float*)d_in[9];
  const float* bv = (const float*)d_in[10];
  const float* Wo = (const float*)d_in[11];
  const float* bo = (const float*)d_in[12];
  const float* btab = (const float*)d_in[13];

  char* ws = (char*)d_ws;
  bf16* qb  = (bf16*)(ws + 0);
  bf16* kb  = (bf16*)(ws + 4194304);
  bf16* vb  = (bf16*)(ws + 20971520);
  bf16* Wqb = (bf16*)(ws + 37748736);
  bf16* Wkb = (bf16*)(ws + 39845888);
  bf16* Wvb = (bf16*)(ws + 41943040);
  bf16* Wob = (bf16*)(ws + 44040192);
  bf16* Qh  = (bf16*)(ws + 46137344);
  bf16* Kh  = (bf16*)(ws + 50331648);
  bf16* Vt  = (bf16*)(ws + 67108864);
  short* pkd = (short*)(ws + 83886080);
  bf16* Ob  = (bf16*)(ws + 92274688);
  // btabT overlays the START of the Ob region: written by fused_cvt, read by
  // attn6, and only THEN overwritten by attn_combine (stream-ordered — safe).
  float* btabT = (float*)(ws + 92274688);      // 57,600 B
  // Opart/L overlay qb/kb region (dead after the projection GEMMs)
  float* Opart = (float*)(ws + 0);             // 16,777,216 B (2 z-halves)
  float* L     = (float*)(ws + 16777216);      //    262,144 B
  (void)ws_size; (void)in_sizes; (void)n_in; (void)out_size;

  hipLaunchKernelGGL(fused_cvt, dim3(26625), dim3(256), 0, stream,
                     q, k, v, bidx, mask, Wq, Wk, Wv, Wo, btab,
                     qb, kb, vb, Wqb, Wkb, Wvb, Wob, pkd, btabT);

  hipLaunchKernelGGL((gemm_bt<0, 64>), dim3(32, 8), dim3(256), 0, stream,
                     qb, Wqb, bq, (void*)Qh, 2048, 1024, 1024, LQ);
  hipLaunchKernelGGL((gemm_bt<0, 128>), dim3(64, 8), dim3(256), 0, stream,
                     kb, Wkb, bk, (void*)Kh, 8192, 1024, 1024, LK);
  hipLaunchKernelGGL((gemm_bt<1, 128>), dim3(64, 8), dim3(256), 0, stream,
                     vb, Wvb, bv, (void*)Vt, 8192, 1024, 1024, LK);

  hipLaunchKernelGGL(attn6, dim3(BSZ * H, LQ / 64, 2), dim3(256), 0, stream,
                     Qh, Kh, Vt, pkd, btabT, Opart, L);
  hipLaunchKernelGGL(attn_combine, dim3(2048), dim3(256), 0, stream,
                     Opart, L, Ob);

  hipLaunchKernelGGL((gemm_bt<2, 64>), dim3(32, 8), dim3(256), 0, stream,
                     Ob, Wob, bo, d_out, 2048, 1024, 1024, LQ);
}